// Round 16
// baseline (371.575 us; speedup 1.0000x reference)
//
#include <hip/hip_runtime.h>
#include <hip/hip_bf16.h>

#define T_SEQ 8192
#define NE 1024
#define FF 4096

typedef __bf16 bf16_t;
typedef __bf16 bf16x8 __attribute__((ext_vector_type(8)));
typedef __bf16 bf16x4 __attribute__((ext_vector_type(4)));
typedef float f32x4 __attribute__((ext_vector_type(4)));

__device__ __forceinline__ void gll16(const void* g, void* l) {
    __builtin_amdgcn_global_load_lds(
        (const __attribute__((address_space(1))) void*)g,
        (__attribute__((address_space(3))) void*)l, 16, 0, 0);
}

// ---------------- elementwise cast fp32 -> bf16 (x4 per thread) ----------------
__global__ __launch_bounds__(256) void cast_f32_bf16(const float* __restrict__ in,
                                                     bf16_t* __restrict__ out, int n4) {
    int i = blockIdx.x * 256 + threadIdx.x;
    if (i >= n4) return;
    float4 v = ((const float4*)in)[i];
    bf16x4 h;
    h[0] = (bf16_t)v.x; h[1] = (bf16_t)v.y; h[2] = (bf16_t)v.z; h[3] = (bf16_t)v.w;
    ((bf16x4*)out)[i] = h;
}

// ---------------- build packed [Wk | Wq*0.125 | Wv | 0pad] as (256 x 1024) bf16, N-major ----------------
__global__ __launch_bounds__(256) void build_wkqv(const float* __restrict__ Wk,
                                                  const float* __restrict__ Wq,
                                                  const float* __restrict__ Wv,
                                                  bf16_t* __restrict__ out) {
    int idx = blockIdx.x * 256 + threadIdx.x;   // over 256*1024
    int n  = idx >> 10;   // 0..255  (output head-col)
    int kk = idx & 1023;  // 0..1023 (embd)
    float v = 0.f;
    if (n < 64)       v = Wk[kk * 64 + n];
    else if (n < 128) v = Wq[kk * 64 + (n - 64)] * 0.125f;  // fold 1/sqrt(hs)
    else if (n < 192) v = Wv[kk * 64 + (n - 128)];
    out[idx] = (bf16_t)v;
}

// ---------------- tiled transpose + cast: in (R x C) f32 -> out (C x R) bf16 ----------------
__global__ __launch_bounds__(256) void tcast(const float* __restrict__ in,
                                             bf16_t* __restrict__ out, int R, int C) {
    __shared__ bf16_t tl[64][66];
    const int bc = blockIdx.x << 6, br = blockIdx.y << 6;
    const int tx = threadIdx.x & 63, ty = threadIdx.x >> 6;
#pragma unroll
    for (int j = 0; j < 16; ++j) {
        const int r = ty + j * 4;
        tl[r][tx] = (bf16_t)in[(size_t)(br + r) * C + bc + tx];
    }
    __syncthreads();
#pragma unroll
    for (int j = 0; j < 16; ++j) {
        const int r = ty + j * 4;
        out[(size_t)(bc + r) * R + br + tx] = tl[tx][r];
    }
}

// ---------------- legacy 128x128 GEMM (kept for QKV + proj epilogues) ----------
template <int EPI>
__global__ __launch_bounds__(256, 2)
void gemm_bt(const bf16_t* __restrict__ A, const bf16_t* __restrict__ Bt,
             int M, int N, int K,
             float* __restrict__ outf,
             bf16_t* __restrict__ ob0, bf16_t* __restrict__ ob1, bf16_t* __restrict__ ob2,
             const float* __restrict__ res, const float* __restrict__ bias) {
    const int tid  = threadIdx.x;
    const int lane = tid & 63;
    const int tiles_n = N >> 7;
    const int tm = blockIdx.x / tiles_n;
    const int tn = blockIdx.x % tiles_n;
    const int brow = tm << 7, bcol = tn << 7;

    __shared__ __align__(16) bf16_t As[128 * 32];
    __shared__ __align__(16) bf16_t Bs[128 * 32];

    const int c1 = tid, c2 = tid + 256;
    const int s1 = (((c1 & 3) ^ ((c1 >> 3) & 3)) * 8);
    const int s2 = (((c2 & 3) ^ ((c2 >> 3) & 3)) * 8);
    const bf16_t* gA1 = A + (size_t)(brow + (c1 >> 2)) * K + s1;
    const bf16_t* gA2 = A + (size_t)(brow + (c2 >> 2)) * K + s2;
    const bf16_t* gB1 = Bt + (size_t)(bcol + (c1 >> 2)) * K + s1;
    const bf16_t* gB2 = Bt + (size_t)(bcol + (c2 >> 2)) * K + s2;
    bf16_t* lA1 = As + c1 * 8; bf16_t* lA2 = As + c2 * 8;
    bf16_t* lB1 = Bs + c1 * 8; bf16_t* lB2 = Bs + c2 * 8;

    const int wv = tid >> 6;
    const int wr = (wv >> 1) * 64, wc = (wv & 1) * 64;
    const int arow  = wr + (lane & 15);
    const int brf   = wc + (lane & 15);
    const int koff = (((lane >> 4) ^ ((lane >> 1) & 3)) * 8);

    f32x4 acc[4][4];
#pragma unroll
    for (int i = 0; i < 4; ++i)
#pragma unroll
        for (int j = 0; j < 4; ++j) acc[i][j] = (f32x4){0.f, 0.f, 0.f, 0.f};

    for (int k0 = 0; k0 < K; k0 += 32) {
        gll16(gA1, lA1); gll16(gA2, lA2);
        gll16(gB1, lB1); gll16(gB2, lB2);
        gA1 += 32; gA2 += 32; gB1 += 32; gB2 += 32;
        __syncthreads();
        bf16x8 af[4], bfr[4];
#pragma unroll
        for (int mi = 0; mi < 4; ++mi)
            af[mi] = *(const bf16x8*)(As + (arow + mi * 16) * 32 + koff);
#pragma unroll
        for (int ni = 0; ni < 4; ++ni)
            bfr[ni] = *(const bf16x8*)(Bs + (brf + ni * 16) * 32 + koff);
#pragma unroll
        for (int mi = 0; mi < 4; ++mi)
#pragma unroll
            for (int ni = 0; ni < 4; ++ni)
                acc[mi][ni] = __builtin_amdgcn_mfma_f32_16x16x32_bf16(
                    af[mi], bfr[ni], acc[mi][ni], 0, 0, 0);
        __syncthreads();
    }

    const int r0 = brow + wr + ((lane >> 4) << 2);
    const int c0 = bcol + wc + (lane & 15);
#pragma unroll
    for (int mi = 0; mi < 4; ++mi)
#pragma unroll
        for (int ni = 0; ni < 4; ++ni)
#pragma unroll
            for (int r = 0; r < 4; ++r) {
                const int row = r0 + mi * 16 + r;
                const int col = c0 + ni * 16;
                const float v = acc[mi][ni][r];
                if constexpr (EPI == 0) {
                    if (col < 64)       ob0[row * 64 + col] = (bf16_t)v;             // k
                    else if (col < 128) ob1[row * 64 + (col - 64)] = (bf16_t)v;      // q (pre-scaled)
                    else if (col < 192) ob2[(size_t)(col - 128) * T_SEQ + row] = (bf16_t)v; // v^T
                } else if constexpr (EPI == 1) {
                    outf[(size_t)row * N + col] = res[(size_t)row * N + col] + v;
                } else if constexpr (EPI == 2) {
                    ob0[(size_t)row * N + col] = (bf16_t)fmaxf(v + bias[col], 0.f);
                } else {
                    outf[(size_t)row * N + col] = res[(size_t)row * N + col] + v + bias[col];
                }
            }
}

// ---------------- 256x256 LDS-staged GEMM, BK=32 subtiles, depth-2 pipeline ----------
// R6/R9-verified best. EPI 2: ob = bf16(relu(C + bias));
// EPI 4: split-K partial; y==0 folds residual+bias: po0 = C + res + bias (the extra
// reads ride in the compute-bound GEMM, HBM ~19%); y==1: po1 = C.
template <int EPI>
__global__ __launch_bounds__(512, 1)
void gemm_ls(const bf16_t* __restrict__ A, int lda,
             const bf16_t* __restrict__ Bt, int ldb,
             int N, int K,
             bf16_t* __restrict__ ob, const float* __restrict__ bias,
             const float* __restrict__ res,
             float* __restrict__ po0, float* __restrict__ po1) {
    __shared__ __align__(16) bf16_t sA[4][8192];
    __shared__ __align__(16) bf16_t sB[4][8192];
    const int tid = threadIdx.x, lane = tid & 63, w = tid >> 6;
    const int wm = w >> 2, wn = w & 3;
    const int nwg = gridDim.x;
    const int wgid = (blockIdx.x & 7) * (nwg >> 3) + (blockIdx.x >> 3);
    const int tiles_n = N >> 8;
    const int tm = wgid / tiles_n, tn = wgid % tiles_n;
    const int brow = tm << 8, bcol = tn << 8;
    const size_t kofs = (size_t)blockIdx.y * K;
    const int s0 = (w & 1) * 2, rbb = w >> 1;
    const bf16_t* gA0 = A + (size_t)(brow + rbb * 64 + lane) * lda + kofs + s0 * 8;
    const bf16_t* gB0 = Bt + (size_t)(bcol + rbb * 64 + lane) * ldb + kofs + s0 * 8;
    const int dA0 = s0 * 2048 + (rbb * 64 + lane) * 8;
    const int l15 = lane & 15, sq = lane >> 4;
    const int aoff = sq * 2048 + (wm * 128 + l15) * 8;
    const int boff = sq * 2048 + (wn * 64 + l15) * 8;
    const int NTS = K >> 5;
    f32x4 acc[8][4];
#pragma unroll
    for (int i = 0; i < 8; ++i)
#pragma unroll
        for (int j = 0; j < 4; ++j) acc[i][j] = (f32x4){0.f, 0.f, 0.f, 0.f};
    bf16x8 af[8], bfr[4];
#define L_SB  __builtin_amdgcn_sched_barrier(0)
#define L_BAR { L_SB; __builtin_amdgcn_s_barrier(); L_SB; }
#define L_LG0 { asm volatile("s_waitcnt lgkmcnt(0)" ::: "memory"); L_SB; }
#define L_VM4 { asm volatile("s_waitcnt vmcnt(4)" ::: "memory"); L_SB; }
#define L_VM0 { asm volatile("s_waitcnt vmcnt(0)" ::: "memory"); L_SB; }
#define L_STAGE(t) { const int q_ = (t) & 3; \
    gll16(gA0 + (size_t)(t) * 32,        &sA[q_][dA0]); \
    gll16(gA0 + (size_t)(t) * 32 + 8,    &sA[q_][dA0 + 2048]); \
    gll16(gB0 + (size_t)(t) * 32,        &sB[q_][dA0]); \
    gll16(gB0 + (size_t)(t) * 32 + 8,    &sB[q_][dA0 + 2048]); \
    L_SB; }
#define L_DS(t) { const int q_ = (t) & 3; \
    _Pragma("unroll") for (int m = 0; m < 8; ++m) \
        af[m] = *(const bf16x8*)(&sA[q_][aoff + m * 128]); \
    _Pragma("unroll") for (int n = 0; n < 4; ++n) \
        bfr[n] = *(const bf16x8*)(&sB[q_][boff + n * 128]); }
#define L_MMA() { __builtin_amdgcn_s_setprio(1); \
    _Pragma("unroll") for (int m = 0; m < 8; ++m) \
    _Pragma("unroll") for (int n = 0; n < 4; ++n) \
        acc[m][n] = __builtin_amdgcn_mfma_f32_16x16x32_bf16(af[m], bfr[n], acc[m][n], 0, 0, 0); \
    __builtin_amdgcn_s_setprio(0); }
    L_STAGE(0); L_STAGE(1);
    L_VM4; L_BAR;
    for (int t = 0; t < NTS - 2; ++t) {
        L_DS(t);
        L_STAGE(t + 2);
        L_LG0;
        L_MMA();
        L_VM4; L_BAR;
    }
    L_DS(NTS - 2); L_LG0; L_MMA(); L_VM0; L_BAR;
    L_DS(NTS - 1); L_LG0; L_MMA();
#undef L_MMA
#undef L_DS
#undef L_STAGE
#undef L_VM0
#undef L_VM4
#undef L_LG0
#undef L_BAR
#undef L_SB
    const int r0 = brow + wm * 128 + sq * 4;
    const int c0 = bcol + wn * 64 + l15;
#pragma unroll
    for (int m = 0; m < 8; ++m)
#pragma unroll
        for (int n = 0; n < 4; ++n) {
            const int col = c0 + n * 16;
#pragma unroll
            for (int r = 0; r < 4; ++r) {
                const int row = r0 + m * 16 + r;
                const float v = acc[m][n][r];
                if constexpr (EPI == 2) {
                    ob[(size_t)row * N + col] = (bf16_t)fmaxf(v + bias[col], 0.f);
                } else {
                    if (blockIdx.y == 0)
                        po0[(size_t)row * N + col] =
                            v + res[(size_t)row * N + col] + bias[col];
                    else
                        po1[(size_t)row * N + col] = v;
                }
            }
        }
}

// ---------------- split-KV flash attention partials, KVBLK=128 (R9-verified) ----
__global__ __launch_bounds__(256)
void attn_partial(const bf16_t* __restrict__ Q, const bf16_t* __restrict__ Kb,
                  const bf16_t* __restrict__ VT,
                  float* __restrict__ po, float* __restrict__ pml) {
    const int tid = threadIdx.x, lane = tid & 63, w = tid >> 6;
    const int j = blockIdx.x * 4 + w;           // job id, 0..4351

    int a = 0;
    while (j >= 16 * (a + 1) * (a + 2)) ++a;    // a in 0..15
    const int r_in = j - 16 * a * (a + 1);
    const int idx = r_in / (a + 1);             // 0..31
    const int chunk = r_in - idx * (a + 1);     // 0..a
    const int g = a * 8 + (idx >> 2);           // diag 64-col tile 0..127
    const int qi = g * 4 + (idx & 3);           // q-subtile 0..511
    const int G = g >> 1;                       // diag 128-col tile 0..63

    __shared__ __align__(16) bf16_t P[4][16 * 128];
    const int l15 = lane & 15, hi = lane >> 4;
    const int koff = hi * 8;
    const int qrow = qi * 16 + l15;
    const bf16x8 qf0 = *(const bf16x8*)(Q + qrow * 64 + koff);
    const bf16x8 qf1 = *(const bf16x8*)(Q + qrow * 64 + 32 + koff);

    float m_run[4], l_run[4];
    f32x4 oacc[4];
#pragma unroll
    for (int r = 0; r < 4; ++r) { m_run[r] = -1e30f; l_run[r] = 0.f; }
#pragma unroll
    for (int d = 0; d < 4; ++d) oacc[d] = (f32x4){0.f, 0.f, 0.f, 0.f};

    const int t0 = chunk * 4;
    const int t1 = min(t0 + 4, G + 1);
    for (int t = t0; t < t1; ++t) {
        const int kv0 = t << 7;
        f32x4 s[8];
#pragma unroll
        for (int ni = 0; ni < 8; ++ni) s[ni] = (f32x4){0.f, 0.f, 0.f, 0.f};
#pragma unroll
        for (int ni = 0; ni < 8; ++ni) {
            const bf16_t* kp = Kb + (size_t)(kv0 + ni * 16 + l15) * 64 + koff;
            bf16x8 kf0 = *(const bf16x8*)(kp);
            bf16x8 kf1 = *(const bf16x8*)(kp + 32);
            s[ni] = __builtin_amdgcn_mfma_f32_16x16x32_bf16(qf0, kf0, s[ni], 0, 0, 0);
            s[ni] = __builtin_amdgcn_mfma_f32_16x16x32_bf16(qf1, kf1, s[ni], 0, 0, 0);
        }
        if (t == G) {  // diagonal 128-tile: mask cols > row
#pragma unroll
            for (int ni = 0; ni < 8; ++ni)
#pragma unroll
                for (int r = 0; r < 4; ++r) {
                    const int col = kv0 + ni * 16 + l15;
                    const int row = qi * 16 + hi * 4 + r;
                    if (col > row) s[ni][r] = -1e30f;
                }
        }
        float alpha[4];
#pragma unroll
        for (int r = 0; r < 4; ++r) {
            float vm = fmaxf(fmaxf(fmaxf(s[0][r], s[1][r]), fmaxf(s[2][r], s[3][r])),
                             fmaxf(fmaxf(s[4][r], s[5][r]), fmaxf(s[6][r], s[7][r])));
            vm = fmaxf(vm, __shfl_xor(vm, 1));
            vm = fmaxf(vm, __shfl_xor(vm, 2));
            vm = fmaxf(vm, __shfl_xor(vm, 4));
            vm = fmaxf(vm, __shfl_xor(vm, 8));
            const float mnew = fmaxf(m_run[r], vm);
            float sum = 0.f;
#pragma unroll
            for (int ni = 0; ni < 8; ++ni) {
                const float p = __expf(s[ni][r] - mnew);
                s[ni][r] = p;           // reuse score regs as P
                sum += p;
            }
            sum += __shfl_xor(sum, 1); sum += __shfl_xor(sum, 2);
            sum += __shfl_xor(sum, 4); sum += __shfl_xor(sum, 8);
            alpha[r] = __expf(m_run[r] - mnew);
            l_run[r] = l_run[r] * alpha[r] + sum;
            m_run[r] = mnew;
        }
#pragma unroll
        for (int d = 0; d < 4; ++d)
#pragma unroll
            for (int r = 0; r < 4; ++r) oacc[d][r] *= alpha[r];
        // C-layout -> A-layout via per-wave LDS (wave-local ordering via lgkmcnt)
        asm volatile("s_waitcnt lgkmcnt(0)" ::: "memory");
        __builtin_amdgcn_sched_barrier(0);
#pragma unroll
        for (int ni = 0; ni < 8; ++ni)
#pragma unroll
            for (int r = 0; r < 4; ++r)
                P[w][(hi * 4 + r) * 128 + ni * 16 + l15] = (bf16_t)s[ni][r];
        asm volatile("s_waitcnt lgkmcnt(0)" ::: "memory");
        __builtin_amdgcn_sched_barrier(0);
#pragma unroll
        for (int ks = 0; ks < 4; ++ks) {
            bf16x8 pf = *(const bf16x8*)(&P[w][l15 * 128 + ks * 32 + koff]);
#pragma unroll
            for (int d = 0; d < 4; ++d) {
                bf16x8 vf = *(const bf16x8*)(VT + (size_t)(d * 16 + l15) * T_SEQ + kv0 + ks * 32 + koff);
                oacc[d] = __builtin_amdgcn_mfma_f32_16x16x32_bf16(pf, vf, oacc[d], 0, 0, 0);
            }
        }
    }
#pragma unroll
    for (int d = 0; d < 4; ++d)
#pragma unroll
        for (int r = 0; r < 4; ++r)
            po[(size_t)j * 1024 + (hi * 4 + r) * 64 + d * 16 + l15] = oacc[d][r];
    if (l15 == 0) {
#pragma unroll
        for (int r = 0; r < 4; ++r) {
            pml[(size_t)j * 32 + hi * 4 + r] = m_run[r];
            pml[(size_t)j * 32 + 16 + hi * 4 + r] = l_run[r];
        }
    }
}

// ---------------- combine partials: 256 thr/block, thread=(row, 4 cols), ILP over i ----
__global__ __launch_bounds__(256)
void attn_reduce(const float* __restrict__ po, const float* __restrict__ pml,
                 bf16_t* __restrict__ O) {
    const int qi = blockIdx.x;        // 0..511
    const int tid = threadIdx.x;
    const int row = tid >> 4;         // 0..15
    const int cg = tid & 15;          // 4 cols each
    const int g = qi >> 2;
    const int a = g >> 3;
    const int idx = ((g & 7) << 2) | (qi & 3);
    const int base = 16 * a * (a + 1) + idx * (a + 1);
    const int cnt = a + 1;

    float M = -1e30f;
    for (int i = 0; i < cnt; ++i)
        M = fmaxf(M, pml[(size_t)(base + i) * 32 + row]);
    float L = 0.f;
    f32x4 o = (f32x4){0.f, 0.f, 0.f, 0.f};
    for (int i = 0; i < cnt; ++i) {
        const float m = pml[(size_t)(base + i) * 32 + row];
        const float l = pml[(size_t)(base + i) * 32 + 16 + row];
        const float wgt = __expf(m - M);
        L += l * wgt;
        const f32x4 v = *(const f32x4*)&po[(size_t)(base + i) * 1024 + row * 64 + cg * 4];
#pragma unroll
        for (int u = 0; u < 4; ++u) o[u] += v[u] * wgt;
    }
    const float inv = 1.f / L;
    bf16x4 h;
#pragma unroll
    for (int u = 0; u < 4; ++u) h[u] = (bf16_t)(o[u] * inv);
    *(bf16x4*)(O + (size_t)(qi * 16 + row) * 64 + cg * 4) = h;
}

// ---------------- row LayerNorm (1024 cols), optional bf16 twin output ----------------
__global__ __launch_bounds__(256)
void ln_fused(const float* __restrict__ in, const float* __restrict__ g,
              const float* __restrict__ b, float* __restrict__ o32,
              bf16_t* __restrict__ o16) {
    const int row = blockIdx.x, tid = threadIdx.x;
    const float4 v = ((const float4*)(in + (size_t)row * NE))[tid];
    float s = v.x + v.y + v.z + v.w;
    float ss = v.x * v.x + v.y * v.y + v.z * v.z + v.w * v.w;
#pragma unroll
    for (int off = 1; off < 64; off <<= 1) {
        s  += __shfl_xor(s, off);
        ss += __shfl_xor(ss, off);
    }
    __shared__ float red[8];
    const int wv = tid >> 6, lane = tid & 63;
    if (lane == 0) { red[wv] = s; red[4 + wv] = ss; }
    __syncthreads();
    s  = red[0] + red[1] + red[2] + red[3];
    ss = red[4] + red[5] + red[6] + red[7];
    const float mu = s * (1.f / NE);
    const float rstd = rsqrtf(ss * (1.f / NE) - mu * mu + 1e-5f);
    const float4 gg = ((const float4*)g)[tid];
    const float4 bb = ((const float4*)b)[tid];
    float4 o;
    o.x = (v.x - mu) * rstd * gg.x + bb.x;
    o.y = (v.y - mu) * rstd * gg.y + bb.y;
    o.z = (v.z - mu) * rstd * gg.z + bb.z;
    o.w = (v.w - mu) * rstd * gg.w + bb.w;
    if (o32) ((float4*)(o32 + (size_t)row * NE))[tid] = o;
    if (o16) {
        bf16x4 h;
        h[0] = (bf16_t)o.x; h[1] = (bf16_t)o.y; h[2] = (bf16_t)o.z; h[3] = (bf16_t)o.w;
        *(bf16x4*)(o16 + (size_t)row * NE + tid * 4) = h;
    }
}

// ---------------- final LN over split-K combine: LN(p0 + p1), 2-stream ------
// (residual r1 and bias b2 already folded into p0 by gemm_ls<4> y==0 epilogue)
__global__ __launch_bounds__(256)
void ln_sum(const float* __restrict__ p0, const float* __restrict__ p1,
            const float* __restrict__ g, const float* __restrict__ b,
            float* __restrict__ out) {
    const int row = blockIdx.x, tid = threadIdx.x;
    const size_t off = (size_t)row * NE;
    const float4 q0 = ((const float4*)(p0 + off))[tid];
    const float4 q1 = ((const float4*)(p1 + off))[tid];
    float4 v;
    v.x = q0.x + q1.x;
    v.y = q0.y + q1.y;
    v.z = q0.z + q1.z;
    v.w = q0.w + q1.w;
    float s = v.x + v.y + v.z + v.w;
    float ss = v.x * v.x + v.y * v.y + v.z * v.z + v.w * v.w;
#pragma unroll
    for (int off2 = 1; off2 < 64; off2 <<= 1) {
        s  += __shfl_xor(s, off2);
        ss += __shfl_xor(ss, off2);
    }
    __shared__ float red[8];
    const int wv = tid >> 6, lane = tid & 63;
    if (lane == 0) { red[wv] = s; red[4 + wv] = ss; }
    __syncthreads();
    s  = red[0] + red[1] + red[2] + red[3];
    ss = red[4] + red[5] + red[6] + red[7];
    const float mu = s * (1.f / NE);
    const float rstd = rsqrtf(ss * (1.f / NE) - mu * mu + 1e-5f);
    const float4 gg = ((const float4*)g)[tid];
    const float4 be = ((const float4*)b)[tid];
    float4 o;
    o.x = (v.x - mu) * rstd * gg.x + be.x;
    o.y = (v.y - mu) * rstd * gg.y + be.y;
    o.z = (v.z - mu) * rstd * gg.z + be.z;
    o.w = (v.w - mu) * rstd * gg.w + be.w;
    ((float4*)(out + off))[tid] = o;
}

extern "C" void kernel_launch(void* const* d_in, const int* in_sizes, int n_in,
                              void* d_out, int out_size, void* d_ws, size_t ws_size,
                              hipStream_t stream) {
    (void)in_sizes; (void)n_in; (void)out_size; (void)ws_size;
    const float* x   = (const float*)d_in[0];
    const float* Wk  = (const float*)d_in[1];
    const float* Wq  = (const float*)d_in[2];
    const float* Wv  = (const float*)d_in[3];
    const float* Wp  = (const float*)d_in[4];
    const float* W1  = (const float*)d_in[5];
    const float* b1  = (const float*)d_in[6];
    const float* W2  = (const float*)d_in[7];
    const float* b2  = (const float*)d_in[8];
    const float* g1  = (const float*)d_in[9];
    const float* be1 = (const float*)d_in[10];
    const float* g2  = (const float*)d_in[11];
    const float* be2 = (const float*)d_in[12];
    float* out = (float*)d_out;

    char* ws = (char*)d_ws;
    bf16_t* xb   = (bf16_t*)(ws);                    // 16 MiB  x bf16 (dead after QKV)
    bf16_t* x1b  = (bf16_t*)(ws + 16777216);         // 16 MiB  x1 bf16 (dead after FFN1)
    bf16_t* hb   = (bf16_t*)(ws + 33554432);         // 64 MiB  hidden bf16 (FFN phase)
    float*  po   = (float*)(ws + 33554432);          // 17.8 MiB attn partials (overlaps hb)
    float*  pml  = (float*)(ws + 33554432 + 18874368); // 0.6 MiB m/l partials
    bf16_t* W1t  = (bf16_t*)(ws + 100663296);        // 8 MiB  W1^T (4096x1024)
    bf16_t* W2t  = (bf16_t*)(ws + 109051904);        // 8 MiB  W2^T (1024x4096)
    bf16_t* Wkqv = (bf16_t*)(ws + 117440512);        // 512 KiB (256x1024)
    bf16_t* WpT  = (bf16_t*)(ws + 117964800);        // 128 KiB
    bf16_t* kb   = (bf16_t*)(ws + 118095872);        // 1 MiB
    bf16_t* qb   = (bf16_t*)(ws + 119144448);        // 1 MiB
    bf16_t* vT   = (bf16_t*)(ws + 120193024);        // 1 MiB (64 x 8192)
    bf16_t* a0   = (bf16_t*)(ws + 121241600);        // 1 MiB attn out
    float*  r1   = (float*)(ws + 122290176);         // 32 MiB residual1 / x1
    float*  pk0  = (float*)(ws + 155844608);         // 32 MiB FFN2 k-half 0 (+res+bias)
    float*  pk1  = (float*)(ws);                     // 32 MiB FFN2 k-half 1 (over xb+x1b)

    cast_f32_bf16<<<8192, 256, 0, stream>>>(x, xb, 2097152);
    build_wkqv<<<1024, 256, 0, stream>>>(Wk, Wq, Wv, Wkqv);
    tcast<<<dim3(16, 1), 256, 0, stream>>>(Wp, WpT, 64, 1024);
    tcast<<<dim3(64, 16), 256, 0, stream>>>(W1, W1t, 1024, 4096);
    tcast<<<dim3(16, 64), 256, 0, stream>>>(W2, W2t, 4096, 1024);

    // k,q,v projections (N padded to 256)
    gemm_bt<0><<<64 * 2, 256, 0, stream>>>(xb, Wkqv, 8192, 256, 1024,
                                           nullptr, kb, qb, vT, nullptr, nullptr);
    // causal flash attention: split-KV partials (KVBLK=128) + reduce
    attn_partial<<<1088, 256, 0, stream>>>(qb, kb, vT, po, pml);
    attn_reduce<<<512, 256, 0, stream>>>(po, pml, a0);
    // proj + residual: r1 = x + a0 @ Wp
    gemm_bt<1><<<64 * 8, 256, 0, stream>>>(a0, WpT, 8192, 1024, 64,
                                           r1, nullptr, nullptr, nullptr, x, nullptr);
    // x1 = LN(r1)  (in-place fp32) + bf16 twin
    ln_fused<<<8192, 256, 0, stream>>>(r1, g1, be1, r1, x1b);
    // h = relu(x1 @ W1 + b1)   [256x256 LDS-staged, 512 blocks]
    gemm_ls<2><<<dim3(512, 1), 512, 0, stream>>>(x1b, 1024, W1t, 1024, 4096, 1024,
                                                 hb, b1, nullptr, nullptr, nullptr);
    // h @ W2 split-K x2: pk0 = C0 + r1 + b2 (residual/bias folded), pk1 = C1
    gemm_ls<4><<<dim3(128, 2), 512, 0, stream>>>(hb, 4096, W2t, 4096, 1024, 2048,
                                                 nullptr, b2, r1, pk0, pk1);
    // out = LN(pk0 + pk1)
    ln_sum<<<8192, 256, 0, stream>>>(pk0, pk1, g2, be2, out);
}

// Round 17
// 347.778 us; speedup vs baseline: 1.0684x; 1.0684x over previous
//
#include <hip/hip_runtime.h>
#include <hip/hip_bf16.h>

#define T_SEQ 8192
#define NE 1024
#define FF 4096

typedef __bf16 bf16_t;
typedef __bf16 bf16x8 __attribute__((ext_vector_type(8)));
typedef __bf16 bf16x4 __attribute__((ext_vector_type(4)));
typedef float f32x4 __attribute__((ext_vector_type(4)));

__device__ __forceinline__ void gll16(const void* g, void* l) {
    __builtin_amdgcn_global_load_lds(
        (const __attribute__((address_space(1))) void*)g,
        (__attribute__((address_space(3))) void*)l, 16, 0, 0);
}

// ---------------- elementwise cast fp32 -> bf16 (x4 per thread) ----------------
__global__ __launch_bounds__(256) void cast_f32_bf16(const float* __restrict__ in,
                                                     bf16_t* __restrict__ out, int n4) {
    int i = blockIdx.x * 256 + threadIdx.x;
    if (i >= n4) return;
    float4 v = ((const float4*)in)[i];
    bf16x4 h;
    h[0] = (bf16_t)v.x; h[1] = (bf16_t)v.y; h[2] = (bf16_t)v.z; h[3] = (bf16_t)v.w;
    ((bf16x4*)out)[i] = h;
}

// ---------------- build packed [Wk | Wq*0.125 | Wv | 0pad] as (256 x 1024) bf16, N-major ----------------
__global__ __launch_bounds__(256) void build_wkqv(const float* __restrict__ Wk,
                                                  const float* __restrict__ Wq,
                                                  const float* __restrict__ Wv,
                                                  bf16_t* __restrict__ out) {
    int idx = blockIdx.x * 256 + threadIdx.x;   // over 256*1024
    int n  = idx >> 10;   // 0..255  (output head-col)
    int kk = idx & 1023;  // 0..1023 (embd)
    float v = 0.f;
    if (n < 64)       v = Wk[kk * 64 + n];
    else if (n < 128) v = Wq[kk * 64 + (n - 64)] * 0.125f;  // fold 1/sqrt(hs)
    else if (n < 192) v = Wv[kk * 64 + (n - 128)];
    out[idx] = (bf16_t)v;
}

// ---------------- tiled transpose + cast: in (R x C) f32 -> out (C x R) bf16 ----------------
__global__ __launch_bounds__(256) void tcast(const float* __restrict__ in,
                                             bf16_t* __restrict__ out, int R, int C) {
    __shared__ bf16_t tl[64][66];
    const int bc = blockIdx.x << 6, br = blockIdx.y << 6;
    const int tx = threadIdx.x & 63, ty = threadIdx.x >> 6;
#pragma unroll
    for (int j = 0; j < 16; ++j) {
        const int r = ty + j * 4;
        tl[r][tx] = (bf16_t)in[(size_t)(br + r) * C + bc + tx];
    }
    __syncthreads();
#pragma unroll
    for (int j = 0; j < 16; ++j) {
        const int r = ty + j * 4;
        out[(size_t)(bc + r) * R + br + tx] = tl[tx][r];
    }
}

// ---------------- legacy 128x128 GEMM (kept for QKV + proj epilogues) ----------
template <int EPI>
__global__ __launch_bounds__(256, 2)
void gemm_bt(const bf16_t* __restrict__ A, const bf16_t* __restrict__ Bt,
             int M, int N, int K,
             float* __restrict__ outf,
             bf16_t* __restrict__ ob0, bf16_t* __restrict__ ob1, bf16_t* __restrict__ ob2,
             const float* __restrict__ res, const float* __restrict__ bias) {
    const int tid  = threadIdx.x;
    const int lane = tid & 63;
    const int tiles_n = N >> 7;
    const int tm = blockIdx.x / tiles_n;
    const int tn = blockIdx.x % tiles_n;
    const int brow = tm << 7, bcol = tn << 7;

    __shared__ __align__(16) bf16_t As[128 * 32];
    __shared__ __align__(16) bf16_t Bs[128 * 32];

    const int c1 = tid, c2 = tid + 256;
    const int s1 = (((c1 & 3) ^ ((c1 >> 3) & 3)) * 8);
    const int s2 = (((c2 & 3) ^ ((c2 >> 3) & 3)) * 8);
    const bf16_t* gA1 = A + (size_t)(brow + (c1 >> 2)) * K + s1;
    const bf16_t* gA2 = A + (size_t)(brow + (c2 >> 2)) * K + s2;
    const bf16_t* gB1 = Bt + (size_t)(bcol + (c1 >> 2)) * K + s1;
    const bf16_t* gB2 = Bt + (size_t)(bcol + (c2 >> 2)) * K + s2;
    bf16_t* lA1 = As + c1 * 8; bf16_t* lA2 = As + c2 * 8;
    bf16_t* lB1 = Bs + c1 * 8; bf16_t* lB2 = Bs + c2 * 8;

    const int wv = tid >> 6;
    const int wr = (wv >> 1) * 64, wc = (wv & 1) * 64;
    const int arow  = wr + (lane & 15);
    const int brf   = wc + (lane & 15);
    const int koff = (((lane >> 4) ^ ((lane >> 1) & 3)) * 8);

    f32x4 acc[4][4];
#pragma unroll
    for (int i = 0; i < 4; ++i)
#pragma unroll
        for (int j = 0; j < 4; ++j) acc[i][j] = (f32x4){0.f, 0.f, 0.f, 0.f};

    for (int k0 = 0; k0 < K; k0 += 32) {
        gll16(gA1, lA1); gll16(gA2, lA2);
        gll16(gB1, lB1); gll16(gB2, lB2);
        gA1 += 32; gA2 += 32; gB1 += 32; gB2 += 32;
        __syncthreads();
        bf16x8 af[4], bfr[4];
#pragma unroll
        for (int mi = 0; mi < 4; ++mi)
            af[mi] = *(const bf16x8*)(As + (arow + mi * 16) * 32 + koff);
#pragma unroll
        for (int ni = 0; ni < 4; ++ni)
            bfr[ni] = *(const bf16x8*)(Bs + (brf + ni * 16) * 32 + koff);
#pragma unroll
        for (int mi = 0; mi < 4; ++mi)
#pragma unroll
            for (int ni = 0; ni < 4; ++ni)
                acc[mi][ni] = __builtin_amdgcn_mfma_f32_16x16x32_bf16(
                    af[mi], bfr[ni], acc[mi][ni], 0, 0, 0);
        __syncthreads();
    }

    const int r0 = brow + wr + ((lane >> 4) << 2);
    const int c0 = bcol + wc + (lane & 15);
#pragma unroll
    for (int mi = 0; mi < 4; ++mi)
#pragma unroll
        for (int ni = 0; ni < 4; ++ni)
#pragma unroll
            for (int r = 0; r < 4; ++r) {
                const int row = r0 + mi * 16 + r;
                const int col = c0 + ni * 16;
                const float v = acc[mi][ni][r];
                if constexpr (EPI == 0) {
                    if (col < 64)       ob0[row * 64 + col] = (bf16_t)v;             // k
                    else if (col < 128) ob1[row * 64 + (col - 64)] = (bf16_t)v;      // q (pre-scaled)
                    else if (col < 192) ob2[(size_t)(col - 128) * T_SEQ + row] = (bf16_t)v; // v^T
                } else if constexpr (EPI == 1) {
                    outf[(size_t)row * N + col] = res[(size_t)row * N + col] + v;
                } else if constexpr (EPI == 2) {
                    ob0[(size_t)row * N + col] = (bf16_t)fmaxf(v + bias[col], 0.f);
                } else {
                    outf[(size_t)row * N + col] = res[(size_t)row * N + col] + v + bias[col];
                }
            }
}

// ---------------- 256x256 LDS-staged GEMM, BK=32 subtiles, depth-2 pipeline ----------
// R6/R9/R15-verified best (94 us @ FFN1, MfmaUtil ~30%). 8 structural variants
// (R7/R8/R10/R11/R12/R14/R16-epilogue) all regressed; final operating point.
// EPI 2: ob = bf16(relu(C + bias)); EPI 4: po{y} = C (f32 partial).
template <int EPI>
__global__ __launch_bounds__(512, 1)
void gemm_ls(const bf16_t* __restrict__ A, int lda,
             const bf16_t* __restrict__ Bt, int ldb,
             int N, int K,
             bf16_t* __restrict__ ob, const float* __restrict__ bias,
             float* __restrict__ po0, float* __restrict__ po1) {
    __shared__ __align__(16) bf16_t sA[4][8192];
    __shared__ __align__(16) bf16_t sB[4][8192];
    const int tid = threadIdx.x, lane = tid & 63, w = tid >> 6;
    const int wm = w >> 2, wn = w & 3;
    const int nwg = gridDim.x;
    const int wgid = (blockIdx.x & 7) * (nwg >> 3) + (blockIdx.x >> 3);
    const int tiles_n = N >> 8;
    const int tm = wgid / tiles_n, tn = wgid % tiles_n;
    const int brow = tm << 8, bcol = tn << 8;
    const size_t kofs = (size_t)blockIdx.y * K;
    const int s0 = (w & 1) * 2, rbb = w >> 1;
    const bf16_t* gA0 = A + (size_t)(brow + rbb * 64 + lane) * lda + kofs + s0 * 8;
    const bf16_t* gB0 = Bt + (size_t)(bcol + rbb * 64 + lane) * ldb + kofs + s0 * 8;
    const int dA0 = s0 * 2048 + (rbb * 64 + lane) * 8;
    const int l15 = lane & 15, sq = lane >> 4;
    const int aoff = sq * 2048 + (wm * 128 + l15) * 8;
    const int boff = sq * 2048 + (wn * 64 + l15) * 8;
    const int NTS = K >> 5;
    f32x4 acc[8][4];
#pragma unroll
    for (int i = 0; i < 8; ++i)
#pragma unroll
        for (int j = 0; j < 4; ++j) acc[i][j] = (f32x4){0.f, 0.f, 0.f, 0.f};
    bf16x8 af[8], bfr[4];
#define L_SB  __builtin_amdgcn_sched_barrier(0)
#define L_BAR { L_SB; __builtin_amdgcn_s_barrier(); L_SB; }
#define L_LG0 { asm volatile("s_waitcnt lgkmcnt(0)" ::: "memory"); L_SB; }
#define L_VM4 { asm volatile("s_waitcnt vmcnt(4)" ::: "memory"); L_SB; }
#define L_VM0 { asm volatile("s_waitcnt vmcnt(0)" ::: "memory"); L_SB; }
#define L_STAGE(t) { const int q_ = (t) & 3; \
    gll16(gA0 + (size_t)(t) * 32,        &sA[q_][dA0]); \
    gll16(gA0 + (size_t)(t) * 32 + 8,    &sA[q_][dA0 + 2048]); \
    gll16(gB0 + (size_t)(t) * 32,        &sB[q_][dA0]); \
    gll16(gB0 + (size_t)(t) * 32 + 8,    &sB[q_][dA0 + 2048]); \
    L_SB; }
#define L_DS(t) { const int q_ = (t) & 3; \
    _Pragma("unroll") for (int m = 0; m < 8; ++m) \
        af[m] = *(const bf16x8*)(&sA[q_][aoff + m * 128]); \
    _Pragma("unroll") for (int n = 0; n < 4; ++n) \
        bfr[n] = *(const bf16x8*)(&sB[q_][boff + n * 128]); }
#define L_MMA() { __builtin_amdgcn_s_setprio(1); \
    _Pragma("unroll") for (int m = 0; m < 8; ++m) \
    _Pragma("unroll") for (int n = 0; n < 4; ++n) \
        acc[m][n] = __builtin_amdgcn_mfma_f32_16x16x32_bf16(af[m], bfr[n], acc[m][n], 0, 0, 0); \
    __builtin_amdgcn_s_setprio(0); }
    L_STAGE(0); L_STAGE(1);
    L_VM4; L_BAR;
    for (int t = 0; t < NTS - 2; ++t) {
        L_DS(t);
        L_STAGE(t + 2);
        L_LG0;
        L_MMA();
        L_VM4; L_BAR;
    }
    L_DS(NTS - 2); L_LG0; L_MMA(); L_VM0; L_BAR;
    L_DS(NTS - 1); L_LG0; L_MMA();
#undef L_MMA
#undef L_DS
#undef L_STAGE
#undef L_VM0
#undef L_VM4
#undef L_LG0
#undef L_BAR
#undef L_SB
    const int r0 = brow + wm * 128 + sq * 4;
    const int c0 = bcol + wn * 64 + l15;
    float* po = blockIdx.y ? po1 : po0;
#pragma unroll
    for (int m = 0; m < 8; ++m)
#pragma unroll
        for (int n = 0; n < 4; ++n) {
            const int col = c0 + n * 16;
#pragma unroll
            for (int r = 0; r < 4; ++r) {
                const int row = r0 + m * 16 + r;
                const float v = acc[m][n][r];
                if constexpr (EPI == 2) {
                    ob[(size_t)row * N + col] = (bf16_t)fmaxf(v + bias[col], 0.f);
                } else {
                    po[(size_t)row * N + col] = v;
                }
            }
        }
}

// ---------------- split-KV flash attention partials, KVBLK=128 (R9-verified) ----
__global__ __launch_bounds__(256)
void attn_partial(const bf16_t* __restrict__ Q, const bf16_t* __restrict__ Kb,
                  const bf16_t* __restrict__ VT,
                  float* __restrict__ po, float* __restrict__ pml) {
    const int tid = threadIdx.x, lane = tid & 63, w = tid >> 6;
    const int j = blockIdx.x * 4 + w;           // job id, 0..4351

    int a = 0;
    while (j >= 16 * (a + 1) * (a + 2)) ++a;    // a in 0..15
    const int r_in = j - 16 * a * (a + 1);
    const int idx = r_in / (a + 1);             // 0..31
    const int chunk = r_in - idx * (a + 1);     // 0..a
    const int g = a * 8 + (idx >> 2);           // diag 64-col tile 0..127
    const int qi = g * 4 + (idx & 3);           // q-subtile 0..511
    const int G = g >> 1;                       // diag 128-col tile 0..63

    __shared__ __align__(16) bf16_t P[4][16 * 128];
    const int l15 = lane & 15, hi = lane >> 4;
    const int koff = hi * 8;
    const int qrow = qi * 16 + l15;
    const bf16x8 qf0 = *(const bf16x8*)(Q + qrow * 64 + koff);
    const bf16x8 qf1 = *(const bf16x8*)(Q + qrow * 64 + 32 + koff);

    float m_run[4], l_run[4];
    f32x4 oacc[4];
#pragma unroll
    for (int r = 0; r < 4; ++r) { m_run[r] = -1e30f; l_run[r] = 0.f; }
#pragma unroll
    for (int d = 0; d < 4; ++d) oacc[d] = (f32x4){0.f, 0.f, 0.f, 0.f};

    const int t0 = chunk * 4;
    const int t1 = min(t0 + 4, G + 1);
    for (int t = t0; t < t1; ++t) {
        const int kv0 = t << 7;
        f32x4 s[8];
#pragma unroll
        for (int ni = 0; ni < 8; ++ni) s[ni] = (f32x4){0.f, 0.f, 0.f, 0.f};
#pragma unroll
        for (int ni = 0; ni < 8; ++ni) {
            const bf16_t* kp = Kb + (size_t)(kv0 + ni * 16 + l15) * 64 + koff;
            bf16x8 kf0 = *(const bf16x8*)(kp);
            bf16x8 kf1 = *(const bf16x8*)(kp + 32);
            s[ni] = __builtin_amdgcn_mfma_f32_16x16x32_bf16(qf0, kf0, s[ni], 0, 0, 0);
            s[ni] = __builtin_amdgcn_mfma_f32_16x16x32_bf16(qf1, kf1, s[ni], 0, 0, 0);
        }
        if (t == G) {  // diagonal 128-tile: mask cols > row
#pragma unroll
            for (int ni = 0; ni < 8; ++ni)
#pragma unroll
                for (int r = 0; r < 4; ++r) {
                    const int col = kv0 + ni * 16 + l15;
                    const int row = qi * 16 + hi * 4 + r;
                    if (col > row) s[ni][r] = -1e30f;
                }
        }
        float alpha[4];
#pragma unroll
        for (int r = 0; r < 4; ++r) {
            float vm = fmaxf(fmaxf(fmaxf(s[0][r], s[1][r]), fmaxf(s[2][r], s[3][r])),
                             fmaxf(fmaxf(s[4][r], s[5][r]), fmaxf(s[6][r], s[7][r])));
            vm = fmaxf(vm, __shfl_xor(vm, 1));
            vm = fmaxf(vm, __shfl_xor(vm, 2));
            vm = fmaxf(vm, __shfl_xor(vm, 4));
            vm = fmaxf(vm, __shfl_xor(vm, 8));
            const float mnew = fmaxf(m_run[r], vm);
            float sum = 0.f;
#pragma unroll
            for (int ni = 0; ni < 8; ++ni) {
                const float p = __expf(s[ni][r] - mnew);
                s[ni][r] = p;           // reuse score regs as P
                sum += p;
            }
            sum += __shfl_xor(sum, 1); sum += __shfl_xor(sum, 2);
            sum += __shfl_xor(sum, 4); sum += __shfl_xor(sum, 8);
            alpha[r] = __expf(m_run[r] - mnew);
            l_run[r] = l_run[r] * alpha[r] + sum;
            m_run[r] = mnew;
        }
#pragma unroll
        for (int d = 0; d < 4; ++d)
#pragma unroll
            for (int r = 0; r < 4; ++r) oacc[d][r] *= alpha[r];
        // C-layout -> A-layout via per-wave LDS (wave-local ordering via lgkmcnt)
        asm volatile("s_waitcnt lgkmcnt(0)" ::: "memory");
        __builtin_amdgcn_sched_barrier(0);
#pragma unroll
        for (int ni = 0; ni < 8; ++ni)
#pragma unroll
            for (int r = 0; r < 4; ++r)
                P[w][(hi * 4 + r) * 128 + ni * 16 + l15] = (bf16_t)s[ni][r];
        asm volatile("s_waitcnt lgkmcnt(0)" ::: "memory");
        __builtin_amdgcn_sched_barrier(0);
#pragma unroll
        for (int ks = 0; ks < 4; ++ks) {
            bf16x8 pf = *(const bf16x8*)(&P[w][l15 * 128 + ks * 32 + koff]);
#pragma unroll
            for (int d = 0; d < 4; ++d) {
                bf16x8 vf = *(const bf16x8*)(VT + (size_t)(d * 16 + l15) * T_SEQ + kv0 + ks * 32 + koff);
                oacc[d] = __builtin_amdgcn_mfma_f32_16x16x32_bf16(pf, vf, oacc[d], 0, 0, 0);
            }
        }
    }
#pragma unroll
    for (int d = 0; d < 4; ++d)
#pragma unroll
        for (int r = 0; r < 4; ++r)
            po[(size_t)j * 1024 + (hi * 4 + r) * 64 + d * 16 + l15] = oacc[d][r];
    if (l15 == 0) {
#pragma unroll
        for (int r = 0; r < 4; ++r) {
            pml[(size_t)j * 32 + hi * 4 + r] = m_run[r];
            pml[(size_t)j * 32 + 16 + hi * 4 + r] = l_run[r];
        }
    }
}

// ---------------- combine partials: 256 thr/block, thread=(row, 4 cols), ILP over i ----
__global__ __launch_bounds__(256)
void attn_reduce(const float* __restrict__ po, const float* __restrict__ pml,
                 bf16_t* __restrict__ O) {
    const int qi = blockIdx.x;        // 0..511
    const int tid = threadIdx.x;
    const int row = tid >> 4;         // 0..15
    const int cg = tid & 15;          // 4 cols each
    const int g = qi >> 2;
    const int a = g >> 3;
    const int idx = ((g & 7) << 2) | (qi & 3);
    const int base = 16 * a * (a + 1) + idx * (a + 1);
    const int cnt = a + 1;

    float M = -1e30f;
    for (int i = 0; i < cnt; ++i)
        M = fmaxf(M, pml[(size_t)(base + i) * 32 + row]);
    float L = 0.f;
    f32x4 o = (f32x4){0.f, 0.f, 0.f, 0.f};
    for (int i = 0; i < cnt; ++i) {
        const float m = pml[(size_t)(base + i) * 32 + row];
        const float l = pml[(size_t)(base + i) * 32 + 16 + row];
        const float wgt = __expf(m - M);
        L += l * wgt;
        const f32x4 v = *(const f32x4*)&po[(size_t)(base + i) * 1024 + row * 64 + cg * 4];
#pragma unroll
        for (int u = 0; u < 4; ++u) o[u] += v[u] * wgt;
    }
    const float inv = 1.f / L;
    bf16x4 h;
#pragma unroll
    for (int u = 0; u < 4; ++u) h[u] = (bf16_t)(o[u] * inv);
    *(bf16x4*)(O + (size_t)(qi * 16 + row) * 64 + cg * 4) = h;
}

// ---------------- row LayerNorm (1024 cols), optional bf16 twin output ----------------
__global__ __launch_bounds__(256)
void ln_fused(const float* __restrict__ in, const float* __restrict__ g,
              const float* __restrict__ b, float* __restrict__ o32,
              bf16_t* __restrict__ o16) {
    const int row = blockIdx.x, tid = threadIdx.x;
    const float4 v = ((const float4*)(in + (size_t)row * NE))[tid];
    float s = v.x + v.y + v.z + v.w;
    float ss = v.x * v.x + v.y * v.y + v.z * v.z + v.w * v.w;
#pragma unroll
    for (int off = 1; off < 64; off <<= 1) {
        s  += __shfl_xor(s, off);
        ss += __shfl_xor(ss, off);
    }
    __shared__ float red[8];
    const int wv = tid >> 6, lane = tid & 63;
    if (lane == 0) { red[wv] = s; red[4 + wv] = ss; }
    __syncthreads();
    s  = red[0] + red[1] + red[2] + red[3];
    ss = red[4] + red[5] + red[6] + red[7];
    const float mu = s * (1.f / NE);
    const float rstd = rsqrtf(ss * (1.f / NE) - mu * mu + 1e-5f);
    const float4 gg = ((const float4*)g)[tid];
    const float4 bb = ((const float4*)b)[tid];
    float4 o;
    o.x = (v.x - mu) * rstd * gg.x + bb.x;
    o.y = (v.y - mu) * rstd * gg.y + bb.y;
    o.z = (v.z - mu) * rstd * gg.z + bb.z;
    o.w = (v.w - mu) * rstd * gg.w + bb.w;
    if (o32) ((float4*)(o32 + (size_t)row * NE))[tid] = o;
    if (o16) {
        bf16x4 h;
        h[0] = (bf16_t)o.x; h[1] = (bf16_t)o.y; h[2] = (bf16_t)o.z; h[3] = (bf16_t)o.w;
        *(bf16x4*)(o16 + (size_t)row * NE + tid * 4) = h;
    }
}

// ---------------- final LN fused with split-K combine: LN(r1 + p0 + p1 + bias) ------
__global__ __launch_bounds__(256)
void ln_sum(const float* __restrict__ r1, const float* __restrict__ p0,
            const float* __restrict__ p1, const float* __restrict__ bias,
            const float* __restrict__ g, const float* __restrict__ b,
            float* __restrict__ out) {
    const int row = blockIdx.x, tid = threadIdx.x;
    const size_t off = (size_t)row * NE;
    const float4 a = ((const float4*)(r1 + off))[tid];
    const float4 q0 = ((const float4*)(p0 + off))[tid];
    const float4 q1 = ((const float4*)(p1 + off))[tid];
    const float4 bb4 = ((const float4*)bias)[tid];
    float4 v;
    v.x = a.x + q0.x + q1.x + bb4.x;
    v.y = a.y + q0.y + q1.y + bb4.y;
    v.z = a.z + q0.z + q1.z + bb4.z;
    v.w = a.w + q0.w + q1.w + bb4.w;
    float s = v.x + v.y + v.z + v.w;
    float ss = v.x * v.x + v.y * v.y + v.z * v.z + v.w * v.w;
#pragma unroll
    for (int off2 = 1; off2 < 64; off2 <<= 1) {
        s  += __shfl_xor(s, off2);
        ss += __shfl_xor(ss, off2);
    }
    __shared__ float red[8];
    const int wv = tid >> 6, lane = tid & 63;
    if (lane == 0) { red[wv] = s; red[4 + wv] = ss; }
    __syncthreads();
    s  = red[0] + red[1] + red[2] + red[3];
    ss = red[4] + red[5] + red[6] + red[7];
    const float mu = s * (1.f / NE);
    const float rstd = rsqrtf(ss * (1.f / NE) - mu * mu + 1e-5f);
    const float4 gg = ((const float4*)g)[tid];
    const float4 be = ((const float4*)b)[tid];
    float4 o;
    o.x = (v.x - mu) * rstd * gg.x + be.x;
    o.y = (v.y - mu) * rstd * gg.y + be.y;
    o.z = (v.z - mu) * rstd * gg.z + be.z;
    o.w = (v.w - mu) * rstd * gg.w + be.w;
    ((float4*)(out + off))[tid] = o;
}

extern "C" void kernel_launch(void* const* d_in, const int* in_sizes, int n_in,
                              void* d_out, int out_size, void* d_ws, size_t ws_size,
                              hipStream_t stream) {
    (void)in_sizes; (void)n_in; (void)out_size; (void)ws_size;
    const float* x   = (const float*)d_in[0];
    const float* Wk  = (const float*)d_in[1];
    const float* Wq  = (const float*)d_in[2];
    const float* Wv  = (const float*)d_in[3];
    const float* Wp  = (const float*)d_in[4];
    const float* W1  = (const float*)d_in[5];
    const float* b1  = (const float*)d_in[6];
    const float* W2  = (const float*)d_in[7];
    const float* b2  = (const float*)d_in[8];
    const float* g1  = (const float*)d_in[9];
    const float* be1 = (const float*)d_in[10];
    const float* g2  = (const float*)d_in[11];
    const float* be2 = (const float*)d_in[12];
    float* out = (float*)d_out;

    char* ws = (char*)d_ws;
    bf16_t* xb   = (bf16_t*)(ws);                    // 16 MiB  x bf16 (dead after QKV)
    bf16_t* x1b  = (bf16_t*)(ws + 16777216);         // 16 MiB  x1 bf16 (dead after FFN1)
    bf16_t* hb   = (bf16_t*)(ws + 33554432);         // 64 MiB  hidden bf16 (FFN phase)
    float*  po   = (float*)(ws + 33554432);          // 17.8 MiB attn partials (overlaps hb)
    float*  pml  = (float*)(ws + 33554432 + 18874368); // 0.6 MiB m/l partials
    bf16_t* W1t  = (bf16_t*)(ws + 100663296);        // 8 MiB  W1^T (4096x1024)
    bf16_t* W2t  = (bf16_t*)(ws + 109051904);        // 8 MiB  W2^T (1024x4096)
    bf16_t* Wkqv = (bf16_t*)(ws + 117440512);        // 512 KiB (256x1024)
    bf16_t* WpT  = (bf16_t*)(ws + 117964800);        // 128 KiB
    bf16_t* kb   = (bf16_t*)(ws + 118095872);        // 1 MiB
    bf16_t* qb   = (bf16_t*)(ws + 119144448);        // 1 MiB
    bf16_t* vT   = (bf16_t*)(ws + 120193024);        // 1 MiB (64 x 8192)
    bf16_t* a0   = (bf16_t*)(ws + 121241600);        // 1 MiB attn out
    float*  r1   = (float*)(ws + 122290176);         // 32 MiB residual1 / x1
    float*  pk0  = (float*)(ws + 155844608);         // 32 MiB FFN2 k-half 0 partial
    float*  pk1  = (float*)(ws);                     // 32 MiB FFN2 k-half 1 (over xb+x1b)

    cast_f32_bf16<<<8192, 256, 0, stream>>>(x, xb, 2097152);
    build_wkqv<<<1024, 256, 0, stream>>>(Wk, Wq, Wv, Wkqv);
    tcast<<<dim3(16, 1), 256, 0, stream>>>(Wp, WpT, 64, 1024);
    tcast<<<dim3(64, 16), 256, 0, stream>>>(W1, W1t, 1024, 4096);
    tcast<<<dim3(16, 64), 256, 0, stream>>>(W2, W2t, 4096, 1024);

    // k,q,v projections (N padded to 256)
    gemm_bt<0><<<64 * 2, 256, 0, stream>>>(xb, Wkqv, 8192, 256, 1024,
                                           nullptr, kb, qb, vT, nullptr, nullptr);
    // causal flash attention: split-KV partials (KVBLK=128) + reduce
    attn_partial<<<1088, 256, 0, stream>>>(qb, kb, vT, po, pml);
    attn_reduce<<<512, 256, 0, stream>>>(po, pml, a0);
    // proj + residual: r1 = x + a0 @ Wp
    gemm_bt<1><<<64 * 8, 256, 0, stream>>>(a0, WpT, 8192, 1024, 64,
                                           r1, nullptr, nullptr, nullptr, x, nullptr);
    // x1 = LN(r1)  (in-place fp32) + bf16 twin
    ln_fused<<<8192, 256, 0, stream>>>(r1, g1, be1, r1, x1b);
    // h = relu(x1 @ W1 + b1)   [256x256 LDS-staged, 512 blocks]
    gemm_ls<2><<<dim3(512, 1), 512, 0, stream>>>(x1b, 1024, W1t, 1024, 4096, 1024,
                                                 hb, b1, nullptr, nullptr);
    // h @ W2 split-K x2 partials  [256x256 LDS-staged, 128 tiles x 2 k-halves]
    gemm_ls<4><<<dim3(128, 2), 512, 0, stream>>>(hb, 4096, W2t, 4096, 1024, 2048,
                                                 nullptr, nullptr, pk0, pk1);
    // out = LN(r1 + pk0 + pk1 + b2)
    ln_sum<<<8192, 256, 0, stream>>>(r1, pk0, pk1, b2, g2, be2, out);
}